// Round 2
// baseline (69.739 us; speedup 1.0000x reference)
//
#include <hip/hip_runtime.h>
#include <math.h>

#define NLEAVES 8192

// ---- LDS layout (floats) ----
// E: exp(T), transposed + swizzled, float4 units:
//   E4[lr*32 + (lp ^ (lr & 7))] = exp(trans[lp][l][4*r4..+3]),  lr = l*8 + r4
// buf: in-place score rows (exp(v - rowmax)), ROWP-padded
// p0/p1: per-slot partial sums, PARTP-padded
// rm: rowmax double buffer (2 x 32)
constexpr int ROWP  = 36;                     // 144B rows, 16B aligned
constexpr int PARTP = 33;
constexpr int OFF_E   = 0;
constexpr int OFF_BUF = 32768;                // 128 KB of E
constexpr int OFF_P0  = OFF_BUF + 32 * ROWP;
constexpr int OFF_P1  = OFF_P0 + 32 * PARTP;
constexpr int OFF_R   = OFF_P1 + 32 * PARTP;
constexpr int SMEM_F32 = OFF_R + 64;
constexpr size_t SMEM_BYTES = (size_t)SMEM_F32 * 4;   // ~141 KB -> 1 block/CU

// Block `blk` reduces IN consecutive input rows (starting at row blk*IN)
// through LEVELS tree levels entirely in LDS; writes its root row to
// out[blk*32 + lp]. NTOT = global node count at this kernel's input level.
template<int IN, int LEVELS>
__global__ __launch_bounds__(1024)
void tree_kernel(const float* __restrict__ in, float* __restrict__ out,
                 const float* __restrict__ iem, const float* __restrict__ trans,
                 int NTOT) {
    extern __shared__ __align__(16) float sm[];
    float* Ef  = sm + OFF_E;
    float* buf = sm + OFF_BUF;
    float* p0  = sm + OFF_P0;
    float* p1  = sm + OFF_P1;
    float* rm  = sm + OFF_R;

    const int tid = threadIdx.x;
    const int lp  = tid & 31;
    const int q   = tid >> 5;
    const int blk = blockIdx.x;

    // --- build exp(T) in swizzled transposed layout (one-time, ~0.6us) ---
    {
        const float4* t4 = (const float4*)trans;     // t4[lp_s*256 + lr]
        float4* E4 = (float4*)Ef;
        #pragma unroll
        for (int it = 0; it < 8; ++it) {
            const int i = tid + it * 1024;
            const int lp_s = i >> 8, lr = i & 255;
            float4 v = t4[i];
            float4 e;
            e.x = expf(v.x); e.y = expf(v.y); e.z = expf(v.z); e.w = expf(v.w);
            E4[lr * 32 + (lp_s ^ (lr & 7))] = e;     // even 8-lane/quad spread
        }
    }
    // --- leaf prepass: rows -> exp(v - rowmax), rowmax -> rm[parity 0] ---
    if (tid < IN * 32) {
        float v = in[(blk * IN) * 32 + tid];
        float gm = v;
        #pragma unroll
        for (int k = 16; k >= 1; k >>= 1) gm = fmaxf(gm, __shfl_xor(gm, k));
        buf[q * ROWP + lp] = expf(v - gm);
        if (lp == 0) rm[q] = gm;
    }
    __syncthreads();

    #pragma unroll
    for (int k = 1; k <= LEVELS; ++k) {
        const int m      = IN >> k;                      // nodes this level
        const int ntiles = (m >= 2) ? (m >> 1) : 1;      // node-pairs
        const int G      = 32 / ntiles;                  // l-split segments
        const int lgnt   = (ntiles == 8) ? 3 : (ntiles == 4) ? 2
                         : (ntiles == 2) ? 1 : 0;
        const int tile = q & (ntiles - 1);
        const int seg  = q >> lgnt;
        const float* rprev = rm + ((k & 1) ? 0 : 32);
        float*       rnext = rm + ((k & 1) ? 32 : 0);
        // children rows: node0 = 2*tile -> rows (4t,4t+1); node1 -> (4t+2,4t+3)
        const int ra0 = 4 * tile, rb0 = 4 * tile + 1;
        const int ra1 = 4 * tile + 2, rb1 = 4 * tile + 3; // stale-but-finite when m==1

        // right-child rows in registers (aligned b128 reads, 2-addr broadcast)
        float4 b0[8], b1[8];
        {
            const float4* pb0 = (const float4*)(buf + rb0 * ROWP);
            const float4* pb1 = (const float4*)(buf + rb1 * ROWP);
            #pragma unroll
            for (int r = 0; r < 8; ++r) { b0[r] = pb0[r]; b1[r] = pb1[r]; }
        }
        float s0 = 0.f, s1v = 0.f;
        #pragma unroll
        for (int li = 0; li < ntiles; ++li) {
            const int l = seg * ntiles + li;
            const float a0 = buf[ra0 * ROWP + l];
            const float a1 = buf[ra1 * ROWP + l];
            const float4* E4 = (const float4*)Ef + l * 256;
            float u0 = 0.f, u1 = 0.f;
            #pragma unroll
            for (int r4 = 0; r4 < 8; ++r4) {
                const float4 e = E4[r4 * 32 + (lp ^ r4)];   // swizzled read
                u0 = fmaf(b0[r4].x, e.x, u0); u0 = fmaf(b0[r4].y, e.y, u0);
                u0 = fmaf(b0[r4].z, e.z, u0); u0 = fmaf(b0[r4].w, e.w, u0);
                u1 = fmaf(b1[r4].x, e.x, u1); u1 = fmaf(b1[r4].y, e.y, u1);
                u1 = fmaf(b1[r4].z, e.z, u1); u1 = fmaf(b1[r4].w, e.w, u1);
            }
            s0  = fmaf(a0, u0, s0);
            s1v = fmaf(a1, u1, s1v);
        }
        p0[q * PARTP + lp] = s0;
        p1[q * PARTP + lp] = s1v;
        __syncthreads();

        if (tid < m * 32) {
            const int node = q;
            const int tl   = node >> 1;
            const float* pp = (node & 1) ? p1 : p0;
            float acc = 0.f;
            #pragma unroll
            for (int s = 0; s < G; ++s) acc += pp[(s * ntiles + tl) * PARTP + lp];
            const float em = iem[(NLEAVES - 2 * (NTOT >> k) + blk * m + node) * 32 + lp];
            const float raw = em + rprev[2 * node] + rprev[2 * node + 1] + logf(acc);
            if (k == LEVELS) {
                out[blk * 32 + lp] = raw;            // m==1, node==0
            } else {
                float gm = raw;
                #pragma unroll
                for (int kk = 16; kk >= 1; kk >>= 1) gm = fmaxf(gm, __shfl_xor(gm, kk));
                buf[node * ROWP + lp] = expf(raw - gm);   // in-place: safe, phase2 reads only p/rm
                if (lp == 0) rnext[node] = gm;
            }
        }
        __syncthreads();
    }
}

extern "C" void kernel_launch(void* const* d_in, const int* in_sizes, int n_in,
                              void* d_out, int out_size, void* d_ws, size_t ws_size,
                              hipStream_t stream) {
    const float* leaf  = (const float*)d_in[0];   // [8192,32]
    const float* iem   = (const float*)d_in[1];   // [8191,32]
    const float* trans = (const float*)d_in[2];   // [32,32,32]
    float* out = (float*)d_out;                   // [32]

    float* s1 = (float*)d_ws;                     // 256*32 f32
    float* s2 = s1 + 256 * 32;                    // 8*32 f32

    (void)hipFuncSetAttribute((const void*)tree_kernel<32, 5>,
                              hipFuncAttributeMaxDynamicSharedMemorySize,
                              (int)SMEM_BYTES);
    (void)hipFuncSetAttribute((const void*)tree_kernel<8, 3>,
                              hipFuncAttributeMaxDynamicSharedMemorySize,
                              (int)SMEM_BYTES);

    // K1: 8192 leaves -> 256 roots (full chip, 1 block/CU)
    tree_kernel<32, 5><<<256, 1024, SMEM_BYTES, stream>>>(leaf, s1, iem, trans, 8192);
    // K2: 256 -> 8
    tree_kernel<32, 5><<<8, 1024, SMEM_BYTES, stream>>>(s1, s2, iem, trans, 256);
    // K3: 8 -> 1
    tree_kernel<8, 3><<<1, 1024, SMEM_BYTES, stream>>>(s2, out, iem, trans, 8);
}

// Round 3
// 56.923 us; speedup vs baseline: 1.2252x; 1.2252x over previous
//
#include <hip/hip_runtime.h>
#include <math.h>

#define NLEAVES 8192
constexpr int NT    = 512;          // threads/block (8 waves)
constexpr int NSLOT = 16;           // q-slots (32 lanes each)

// ---- LDS layout (floats) ----
// E: exp(T), transposed + swizzled, float4 units:
//   E4[lr*32 + (lp ^ (lr & 7))] = exp(trans[lp][l][4*r4..+3]),  lr = l*8 + r4
constexpr int ROWP  = 36;                      // row pad: 144B, 16B-aligned
constexpr int PARTP = 33;
constexpr int OFF_E   = 0;
constexpr int OFF_BUF = 32768;                 // 128 KB of E
constexpr int OFF_P0  = OFF_BUF + 32 * ROWP;
constexpr int OFF_P1  = OFF_P0 + NSLOT * PARTP;
constexpr int OFF_R   = OFF_P1 + NSLOT * PARTP;
constexpr int SMEM_F32 = OFF_R + 64;
constexpr size_t SMEM_BYTES = (size_t)SMEM_F32 * 4;   // ~137 KB -> 1 block/CU

// Block `blk` reduces IN consecutive score rows (from row blk*IN) through
// LEVELS tree levels in LDS; writes its root row to out[blk*32+lp].
// NTOT = global node count at this kernel's input level.
template<int IN, int LEVELS>
__global__ __launch_bounds__(NT, 1)
void tree_kernel(const float* __restrict__ in, float* __restrict__ out,
                 const float* __restrict__ iem, const float* __restrict__ trans,
                 int NTOT) {
    extern __shared__ __align__(16) float sm[];
    float* Ef  = sm + OFF_E;
    float* buf = sm + OFF_BUF;
    float* p0  = sm + OFF_P0;
    float* p1  = sm + OFF_P1;
    float* rm  = sm + OFF_R;

    const int tid = threadIdx.x;
    const int lp  = tid & 31;
    const int q   = tid >> 5;
    const int blk = blockIdx.x;

    // --- build exp(T), block-rotated first-touch to help L2 miss-merging ---
    {
        const float4* t4 = (const float4*)trans;      // t4[lp_s*256 + lr]
        float4* E4 = (float4*)Ef;
        #pragma unroll
        for (int it = 0; it < 16; ++it) {
            const int idx = (tid + it * NT + blk * 32) & 8191;
            const int lp_s = idx >> 8, lr = idx & 255;
            float4 v = t4[idx];
            float4 e;
            e.x = expf(v.x); e.y = expf(v.y); e.z = expf(v.z); e.w = expf(v.w);
            E4[lr * 32 + (lp_s ^ (lr & 7))] = e;      // swizzled, full-BW write
        }
    }
    // --- leaf prepass: rows -> exp(v - rowmax); rowmax -> rm (parity 0) ---
    for (int rr = q; rr < IN; rr += NSLOT) {
        float v = in[(blk * IN + rr) * 32 + lp];
        float gm = v;
        #pragma unroll
        for (int kk = 16; kk >= 1; kk >>= 1) gm = fmaxf(gm, __shfl_xor(gm, kk));
        buf[rr * ROWP + lp] = expf(v - gm);
        if (lp == 0) rm[rr] = gm;
    }
    __syncthreads();

    #pragma unroll
    for (int k = 1; k <= LEVELS; ++k) {
        const int m      = IN >> k;                       // nodes this level
        const int npairs = (m >= 2) ? (m >> 1) : 1;       // node-pairs
        const int S      = NSLOT / npairs;                // slots per pair
        const int llen   = 32 / S;                        // l-values per slot
        const int lgnp   = (npairs == 8) ? 3 : (npairs == 4) ? 2
                         : (npairs == 2) ? 1 : 0;
        const int tile = q & (npairs - 1);
        const int seg  = q >> lgnp;                       // half-waves share seg -> same l
        const float* rprev = rm + ((k & 1) ? 0 : 32);
        float*       rnext = rm + ((k & 1) ? 32 : 0);
        // children rows: node0 = 2*tile -> rows (4t,4t+1); node1 -> (4t+2,4t+3)
        const int ra0 = 4 * tile, rb0 = 4 * tile + 1;
        const int ra1 = 4 * tile + 2, rb1 = 4 * tile + 3; // stale-but-finite when m==1

        // right-child rows in registers (needs VGPR headroom -> launch_bounds(512,1))
        float4 b0[8], b1[8];
        {
            const float4* pb0 = (const float4*)(buf + rb0 * ROWP);
            const float4* pb1 = (const float4*)(buf + rb1 * ROWP);
            #pragma unroll
            for (int r = 0; r < 8; ++r) { b0[r] = pb0[r]; b1[r] = pb1[r]; }
        }
        float s0 = 0.f, s1v = 0.f;
        #pragma unroll
        for (int li = 0; li < llen; ++li) {
            const int l = seg * llen + li;
            const float a0 = buf[ra0 * ROWP + l];
            const float a1 = buf[ra1 * ROWP + l];
            const float4* E4 = (const float4*)Ef + l * 256;
            float u0 = 0.f, u1 = 0.f;
            #pragma unroll
            for (int r4 = 0; r4 < 8; ++r4) {
                const float4 e = E4[r4 * 32 + (lp ^ r4)];   // swizzled read
                u0 = fmaf(b0[r4].x, e.x, u0); u0 = fmaf(b0[r4].y, e.y, u0);
                u0 = fmaf(b0[r4].z, e.z, u0); u0 = fmaf(b0[r4].w, e.w, u0);
                u1 = fmaf(b1[r4].x, e.x, u1); u1 = fmaf(b1[r4].y, e.y, u1);
                u1 = fmaf(b1[r4].z, e.z, u1); u1 = fmaf(b1[r4].w, e.w, u1);
            }
            s0  = fmaf(a0, u0, s0);
            s1v = fmaf(a1, u1, s1v);
        }
        p0[q * PARTP + lp] = s0;
        p1[q * PARTP + lp] = s1v;
        __syncthreads();

        if (tid < m * 32) {
            const int node = q;
            const int tl   = node >> 1;
            const float* pp = (node & 1) ? p1 : p0;
            float acc = 0.f;
            #pragma unroll
            for (int s = 0; s < S; ++s) acc += pp[(s * npairs + tl) * PARTP + lp];
            const float em = iem[(NLEAVES - 2 * (NTOT >> k) + blk * m + node) * 32 + lp];
            const float raw = em + rprev[2 * node] + rprev[2 * node + 1] + logf(acc);
            if (k == LEVELS) {
                out[blk * 32 + lp] = raw;             // m==1, node==0
            } else {
                float gm = raw;
                #pragma unroll
                for (int kk = 16; kk >= 1; kk >>= 1) gm = fmaxf(gm, __shfl_xor(gm, kk));
                buf[node * ROWP + lp] = expf(raw - gm);   // in-place: safe (phase2 reads only p/rm)
                if (lp == 0) rnext[node] = gm;
            }
        }
        __syncthreads();
    }
}

extern "C" void kernel_launch(void* const* d_in, const int* in_sizes, int n_in,
                              void* d_out, int out_size, void* d_ws, size_t ws_size,
                              hipStream_t stream) {
    const float* leaf  = (const float*)d_in[0];   // [8192,32]
    const float* iem   = (const float*)d_in[1];   // [8191,32]
    const float* trans = (const float*)d_in[2];   // [32,32,32]
    float* out = (float*)d_out;                   // [32]

    float* s1 = (float*)d_ws;                     // 256*32 f32
    float* s2 = s1 + 256 * 32;                    // 8*32 f32

    (void)hipFuncSetAttribute((const void*)tree_kernel<32, 5>,
                              hipFuncAttributeMaxDynamicSharedMemorySize,
                              (int)SMEM_BYTES);
    (void)hipFuncSetAttribute((const void*)tree_kernel<8, 3>,
                              hipFuncAttributeMaxDynamicSharedMemorySize,
                              (int)SMEM_BYTES);

    // K1: 8192 leaves -> 256 roots (full chip, 1 block/CU)
    tree_kernel<32, 5><<<256, NT, SMEM_BYTES, stream>>>(leaf, s1, iem, trans, 8192);
    // K2: 256 -> 8
    tree_kernel<32, 5><<<8, NT, SMEM_BYTES, stream>>>(s1, s2, iem, trans, 256);
    // K3: 8 -> 1
    tree_kernel<8, 3><<<1, NT, SMEM_BYTES, stream>>>(s2, out, iem, trans, 8);
}